// Round 1
// baseline (638.064 us; speedup 1.0000x reference)
//
#include <hip/hip_runtime.h>

typedef __bf16 bf16x8 __attribute__((ext_vector_type(8)));
typedef float f32x4 __attribute__((ext_vector_type(4)));
typedef unsigned int uintx4 __attribute__((ext_vector_type(4)));

// ---------- bf16 helpers (bit-level, no __bf16 scalar arithmetic) ----------
__device__ __forceinline__ float bflo(unsigned int u) { return __uint_as_float(u << 16); }
__device__ __forceinline__ float bfhi(unsigned int u) { return __uint_as_float(u & 0xffff0000u); }
__device__ __forceinline__ unsigned int f2bf(float f) {  // RNE f32 -> bf16 bits
    unsigned int u = __float_as_uint(f);
    return (u + 0x7fffu + ((u >> 16) & 1u)) >> 16;
}
__device__ __forceinline__ unsigned int pack2(float lo, float hi) {
    return (f2bf(hi) << 16) | f2bf(lo);
}

// ---------- setup kernels ----------
__global__ void k_cvt_w(const float* __restrict__ W1, const float* __restrict__ W2,
                        const float* __restrict__ W3, unsigned short* __restrict__ wb1,
                        unsigned short* __restrict__ wb2, unsigned short* __restrict__ wb3) {
    int i = blockIdx.x * blockDim.x + threadIdx.x;
    if (i < 128 * 128) {
        wb1[i] = (unsigned short)f2bf(W1[i]);
        wb2[i] = (unsigned short)f2bf(W2[i]);
        wb3[i] = (unsigned short)f2bf(W3[i]);
    }
}

__global__ void k_cvt_x(const float* __restrict__ x, unsigned int* __restrict__ xb, int n2) {
    int i = blockIdx.x * blockDim.x + threadIdx.x;  // one uint = 2 bf16
    if (i < n2) {
        float2 v = ((const float2*)x)[i];
        xb[i] = pack2(v.x, v.y);
    }
}

__global__ void k_zero(int* __restrict__ counts, float* __restrict__ sums,
                       float* __restrict__ sumsq, int N) {
    int i = blockIdx.x * blockDim.x + threadIdx.x;
    if (i < N) counts[i] = 0;
    if (i < 128) { sums[i] = 0.f; sumsq[i] = 0.f; }
}

__global__ void k_hist(const int* __restrict__ dst, int* __restrict__ counts, int E) {
    for (int e = blockIdx.x * blockDim.x + threadIdx.x; e < E; e += gridDim.x * blockDim.x)
        atomicAdd(&counts[dst[e]], 1);
}

__global__ void k_scanA(const int* __restrict__ counts, int* __restrict__ excl,
                        int* __restrict__ bsums, int N) {
    __shared__ int s[256];
    int t = threadIdx.x;
    int i = blockIdx.x * 256 + t;
    int v = (i < N) ? counts[i] : 0;
    s[t] = v;
    __syncthreads();
    for (int off = 1; off < 256; off <<= 1) {
        int tv = (t >= off) ? s[t - off] : 0;
        __syncthreads();
        s[t] += tv;
        __syncthreads();
    }
    if (i < N) excl[i] = s[t] - v;
    if (t == 255) bsums[blockIdx.x] = s[255];
}

__global__ void k_scanB(int* __restrict__ bsums, int nb) {
    __shared__ int s[512];
    int t = threadIdx.x;
    int v = (t < nb) ? bsums[t] : 0;
    s[t] = v;
    __syncthreads();
    for (int off = 1; off < 512; off <<= 1) {
        int tv = (t >= off) ? s[t - off] : 0;
        __syncthreads();
        s[t] += tv;
        __syncthreads();
    }
    if (t < nb) bsums[t] = s[t] - v;
}

__global__ void k_scanC(const int* __restrict__ counts, int* __restrict__ rowstart,
                        int* __restrict__ cursor, const int* __restrict__ bsums,
                        float* __restrict__ dinv, int N) {
    int i = blockIdx.x * blockDim.x + threadIdx.x;
    if (i < N) {
        int rs = rowstart[i] + bsums[i >> 8];
        rowstart[i] = rs;
        cursor[i] = rs;
        dinv[i] = rsqrtf((float)counts[i] + 1.0f);
    }
}

__global__ void k_fill(const int* __restrict__ src, const int* __restrict__ dst,
                       int* __restrict__ cursor, int* __restrict__ csr, int E) {
    for (int e = blockIdx.x * blockDim.x + threadIdx.x; e < E; e += gridDim.x * blockDim.x) {
        int d = dst[e];
        int pos = atomicAdd(&cursor[d], 1);
        csr[pos] = src[e];
    }
}

// ---------- GEMM: hs[i,c] = (sum_k in[i,k] * W[c,k]) * dinv[i], bf16 in/out ----------
// wave handles 16 rows x 128 cols via mfma_f32_16x16x32_bf16.
// A frag: lane l holds A[row = l&15][k = kc*32 + (l>>4)*8 + i], i=0..7 (16B contiguous)
// B frag: lane l holds W[col = l&15 offset][k = kc*32 + (l>>4)*8 + i]
// D frag: lane l reg q -> col = l&15, row = (l>>4)*4 + q   [HW-verified layout]
__global__ __launch_bounds__(256) void k_gemm(const unsigned short* __restrict__ Ab,
                                              const unsigned short* __restrict__ Wb,
                                              const float* __restrict__ dinv,
                                              unsigned short* __restrict__ hs, int N) {
    int wv = threadIdx.x >> 6;
    int lane = threadIdx.x & 63;
    int ln = lane & 15, hi = lane >> 4;
    int rowbase = blockIdx.x * 64 + wv * 16;

    uintx4 zz = {0u, 0u, 0u, 0u};
    bf16x8 a[4];
    int arow = rowbase + ln;
    bool aok = arow < N;
    const uintx4* Ap = (const uintx4*)(Ab + (size_t)arow * 128 + hi * 8);
#pragma unroll
    for (int kc = 0; kc < 4; ++kc) {
        uintx4 u = aok ? Ap[kc * 4] : zz;
        a[kc] = __builtin_bit_cast(bf16x8, u);
    }

    float dv[4];
    int er0 = rowbase + hi * 4;
#pragma unroll
    for (int q = 0; q < 4; ++q) dv[q] = (er0 + q < N) ? dinv[er0 + q] : 0.f;

#pragma unroll
    for (int ct = 0; ct < 8; ++ct) {
        int col = ct * 16 + ln;
        const uintx4* Wp = (const uintx4*)(Wb + col * 128 + hi * 8);
        f32x4 acc = {0.f, 0.f, 0.f, 0.f};
#pragma unroll
        for (int kc = 0; kc < 4; ++kc) {
            bf16x8 b = __builtin_bit_cast(bf16x8, Wp[kc * 4]);
            acc = __builtin_amdgcn_mfma_f32_16x16x32_bf16(a[kc], b, acc, 0, 0, 0);
        }
#pragma unroll
        for (int q = 0; q < 4; ++q) {
            int r = er0 + q;
            if (r < N) hs[(size_t)r * 128 + col] = (unsigned short)f2bf(acc[q] * dv[q]);
        }
    }
}

// ---------- gather: pre[i] = dinv[i] * (sum_{src in adj(i)} hs[src] + hs[i]) ----------
// One wave per node; lane holds channel pair (2*lane, 2*lane+1). FINAL adds bias, f32 out.
template <int FINAL>
__global__ __launch_bounds__(256) void k_gather(const unsigned int* __restrict__ hs2,
                                                const int* __restrict__ csr,
                                                const int* __restrict__ rowstart,
                                                const int* __restrict__ counts,
                                                const float* __restrict__ dinv,
                                                unsigned int* __restrict__ pre2,
                                                float* __restrict__ outf,
                                                const float* __restrict__ bias, int N) {
    int lane = threadIdx.x & 63;
    int w = blockIdx.x * (blockDim.x >> 6) + (threadIdx.x >> 6);
    int nw = gridDim.x * (blockDim.x >> 6);
    for (int i = w; i < N; i += nw) {
        int st = rowstart[i], cnt = counts[i];
        unsigned int us = hs2[(size_t)i * 64 + lane];  // self term
        float s0 = bflo(us), s1 = bfhi(us);
        int j = 0;
        for (; j + 4 <= cnt; j += 4) {
            int e0 = csr[st + j], e1 = csr[st + j + 1], e2 = csr[st + j + 2], e3 = csr[st + j + 3];
            unsigned int u0 = hs2[(size_t)e0 * 64 + lane];
            unsigned int u1 = hs2[(size_t)e1 * 64 + lane];
            unsigned int u2 = hs2[(size_t)e2 * 64 + lane];
            unsigned int u3 = hs2[(size_t)e3 * 64 + lane];
            s0 += bflo(u0) + bflo(u1) + bflo(u2) + bflo(u3);
            s1 += bfhi(u0) + bfhi(u1) + bfhi(u2) + bfhi(u3);
        }
        for (; j < cnt; ++j) {
            unsigned int u = hs2[(size_t)csr[st + j] * 64 + lane];
            s0 += bflo(u);
            s1 += bfhi(u);
        }
        float sc = dinv[i];
        s0 *= sc;
        s1 *= sc;
        if (FINAL) {
            float2 o;
            o.x = s0 + bias[2 * lane];
            o.y = s1 + bias[2 * lane + 1];
            ((float2*)outf)[(size_t)i * 64 + lane] = o;
        } else {
            pre2[(size_t)i * 64 + lane] = pack2(s0, s1);
        }
    }
}

// ---------- BN stats: per-channel sum/sumsq ----------
__global__ __launch_bounds__(256) void k_stats(const unsigned int* __restrict__ pre2,
                                               float* __restrict__ sums,
                                               float* __restrict__ sumsq, int N) {
    int c2 = threadIdx.x & 63, h = threadIdx.x >> 6;
    int r0 = blockIdx.x * 512;
    int r1 = min(N, r0 + 512);
    float s0 = 0.f, s1 = 0.f, q0 = 0.f, q1 = 0.f;
    for (int r = r0 + h; r < r1; r += 4) {
        unsigned int u = pre2[(size_t)r * 64 + c2];
        float a = bflo(u), b = bfhi(u);
        s0 += a; s1 += b; q0 += a * a; q1 += b * b;
    }
    __shared__ float red[4][64][4];
    red[h][c2][0] = s0; red[h][c2][1] = s1; red[h][c2][2] = q0; red[h][c2][3] = q1;
    __syncthreads();
    if (h == 0) {
        for (int hh = 1; hh < 4; ++hh) {
            s0 += red[hh][c2][0]; s1 += red[hh][c2][1];
            q0 += red[hh][c2][2]; q1 += red[hh][c2][3];
        }
        atomicAdd(&sums[2 * c2], s0);
        atomicAdd(&sums[2 * c2 + 1], s1);
        atomicAdd(&sumsq[2 * c2], q0);
        atomicAdd(&sumsq[2 * c2 + 1], q1);
    }
}

// fold g/beta/mu/istd into per-channel A,B; re-zero stats for next layer
__global__ void k_bnfin(const float* __restrict__ g, const float* __restrict__ beta,
                        float* __restrict__ sums, float* __restrict__ sumsq,
                        float* __restrict__ bnA, float* __restrict__ bnB, float invN) {
    int c = threadIdx.x;
    if (c < 128) {
        float m = sums[c] * invN;
        float var = sumsq[c] * invN - m * m;
        float istd = rsqrtf(var + 1e-5f);
        float A = g[c] * istd;
        bnA[c] = A;
        bnB[c] = beta[c] - m * A;
        sums[c] = 0.f;
        sumsq[c] = 0.f;
    }
}

__global__ __launch_bounds__(256) void k_bnrelu(const unsigned int* __restrict__ pre2,
                                                const float* __restrict__ bnA,
                                                const float* __restrict__ bnB,
                                                unsigned int* __restrict__ act2, int n2) {
    for (int i = blockIdx.x * blockDim.x + threadIdx.x; i < n2; i += gridDim.x * blockDim.x) {
        int c = (i & 63) * 2;
        unsigned int u = pre2[i];
        float a = fmaxf(bflo(u) * bnA[c] + bnB[c], 0.f);
        float b = fmaxf(bfhi(u) * bnA[c + 1] + bnB[c + 1], 0.f);
        act2[i] = pack2(a, b);
    }
}

// ---------- host ----------
extern "C" void kernel_launch(void* const* d_in, const int* in_sizes, int n_in,
                              void* d_out, int out_size, void* d_ws, size_t ws_size,
                              hipStream_t stream) {
    const float* x = (const float*)d_in[0];
    const int* ei = (const int*)d_in[1];
    const float* W1 = (const float*)d_in[2];
    // b1 = d_in[3], b2 = d_in[7]: cancel inside BatchNorm, unused
    const float* g1 = (const float*)d_in[4];
    const float* be1 = (const float*)d_in[5];
    const float* W2 = (const float*)d_in[6];
    const float* g2 = (const float*)d_in[8];
    const float* be2 = (const float*)d_in[9];
    const float* W3 = (const float*)d_in[10];
    const float* b3 = (const float*)d_in[11];

    int N = in_sizes[0] / 128;
    int E = in_sizes[1] / 2;
    const int* srcp = ei;
    const int* dstp = ei + E;

    char* w = (char*)d_ws;
    auto alloc = [&](size_t b) { char* p = w; w += (b + 255) & ~(size_t)255; return p; };
    int* counts = (int*)alloc((size_t)N * 4);
    int* rowstart = (int*)alloc((size_t)N * 4);
    int* cursor = (int*)alloc((size_t)N * 4);
    int* bsums = (int*)alloc(4096);
    float* dinv = (float*)alloc((size_t)N * 4);
    float* sums = (float*)alloc(512);
    float* sumsq = (float*)alloc(512);
    float* bnA = (float*)alloc(512);
    float* bnB = (float*)alloc(512);
    int* csr = (int*)alloc((size_t)E * 4);
    unsigned short* wb1 = (unsigned short*)alloc(16384 * 2);
    unsigned short* wb2 = (unsigned short*)alloc(16384 * 2);
    unsigned short* wb3 = (unsigned short*)alloc(16384 * 2);
    unsigned short* xb = (unsigned short*)alloc((size_t)N * 128 * 2);
    unsigned short* hs = (unsigned short*)alloc((size_t)N * 128 * 2);
    unsigned short* pre = (unsigned short*)alloc((size_t)N * 128 * 2);
    unsigned short* act = (unsigned short*)alloc((size_t)N * 128 * 2);
    (void)ws_size; (void)n_in; (void)out_size;

    int nb = (N + 255) / 256;
    int gemm_grid = (N + 63) / 64;
    float invN = 1.0f / (float)N;

    // graph/CSR setup (graph is identical for all 3 layers)
    k_cvt_w<<<(16384 + 255) / 256, 256, 0, stream>>>(W1, W2, W3, wb1, wb2, wb3);
    k_cvt_x<<<(N * 64 + 255) / 256, 256, 0, stream>>>(x, (unsigned int*)xb, N * 64);
    k_zero<<<nb, 256, 0, stream>>>(counts, sums, sumsq, N);
    k_hist<<<2048, 256, 0, stream>>>(dstp, counts, E);
    k_scanA<<<nb, 256, 0, stream>>>(counts, rowstart, bsums, N);
    k_scanB<<<1, 512, 0, stream>>>(bsums, nb);
    k_scanC<<<nb, 256, 0, stream>>>(counts, rowstart, cursor, bsums, dinv, N);
    k_fill<<<2048, 256, 0, stream>>>(srcp, dstp, cursor, csr, E);

    // layer 1
    k_gemm<<<gemm_grid, 256, 0, stream>>>(xb, wb1, dinv, hs, N);
    k_gather<0><<<2048, 256, 0, stream>>>((const unsigned int*)hs, csr, rowstart, counts, dinv,
                                          (unsigned int*)pre, nullptr, nullptr, N);
    k_stats<<<(N + 511) / 512, 256, 0, stream>>>((const unsigned int*)pre, sums, sumsq, N);
    k_bnfin<<<1, 128, 0, stream>>>(g1, be1, sums, sumsq, bnA, bnB, invN);
    k_bnrelu<<<2048, 256, 0, stream>>>((const unsigned int*)pre, bnA, bnB, (unsigned int*)act,
                                       N * 64);
    // layer 2
    k_gemm<<<gemm_grid, 256, 0, stream>>>(act, wb2, dinv, hs, N);
    k_gather<0><<<2048, 256, 0, stream>>>((const unsigned int*)hs, csr, rowstart, counts, dinv,
                                          (unsigned int*)pre, nullptr, nullptr, N);
    k_stats<<<(N + 511) / 512, 256, 0, stream>>>((const unsigned int*)pre, sums, sumsq, N);
    k_bnfin<<<1, 128, 0, stream>>>(g2, be2, sums, sumsq, bnA, bnB, invN);
    k_bnrelu<<<2048, 256, 0, stream>>>((const unsigned int*)pre, bnA, bnB, (unsigned int*)act,
                                       N * 64);
    // layer 3 (no BN; bias applied, f32 out)
    k_gemm<<<gemm_grid, 256, 0, stream>>>(act, wb3, dinv, hs, N);
    k_gather<1><<<2048, 256, 0, stream>>>((const unsigned int*)hs, csr, rowstart, counts, dinv,
                                          nullptr, (float*)d_out, b3, N);
}

// Round 2
// 462.314 us; speedup vs baseline: 1.3802x; 1.3802x over previous
//
#include <hip/hip_runtime.h>

typedef __bf16 bf16x8 __attribute__((ext_vector_type(8)));
typedef float f32x4 __attribute__((ext_vector_type(4)));
typedef unsigned int uintx4 __attribute__((ext_vector_type(4)));

#define PTILE 4096  // edges per partition block
#define CSRCAP 5120 // per-bucket csr LDS cap (mean 4096, std 64)

// ---------- bf16 helpers ----------
__device__ __forceinline__ float bflo(unsigned int u) { return __uint_as_float(u << 16); }
__device__ __forceinline__ float bfhi(unsigned int u) { return __uint_as_float(u & 0xffff0000u); }
__device__ __forceinline__ unsigned int f2bf(float f) {
    unsigned int u = __float_as_uint(f);
    return (u + 0x7fffu + ((u >> 16) & 1u)) >> 16;
}
__device__ __forceinline__ unsigned int pack2(float lo, float hi) {
    return (f2bf(hi) << 16) | f2bf(lo);
}

// ---------- setup ----------
__global__ void k_cvt_w(const float* __restrict__ W1, const float* __restrict__ W2,
                        const float* __restrict__ W3, unsigned short* __restrict__ wb1,
                        unsigned short* __restrict__ wb2, unsigned short* __restrict__ wb3) {
    int i = blockIdx.x * blockDim.x + threadIdx.x;
    if (i < 128 * 128) {
        wb1[i] = (unsigned short)f2bf(W1[i]);
        wb2[i] = (unsigned short)f2bf(W2[i]);
        wb3[i] = (unsigned short)f2bf(W3[i]);
    }
}

__global__ void k_init(int* __restrict__ bktcnt, float* __restrict__ sums,
                       float* __restrict__ sumsq, int NB) {
    int t = threadIdx.x;
    if (t < NB) bktcnt[t] = 0;
    if (t < 128) { sums[t] = 0.f; sumsq[t] = 0.f; }
}

// bucket histogram: bucket = dst >> 8
__global__ __launch_bounds__(256) void k_bhist(const int* __restrict__ dst,
                                               int* __restrict__ bktcnt, int E, int NB) {
    __shared__ int h[512];
    for (int i = threadIdx.x; i < NB; i += 256) h[i] = 0;
    __syncthreads();
    for (int e = blockIdx.x * blockDim.x + threadIdx.x; e < E; e += gridDim.x * blockDim.x)
        atomicAdd(&h[dst[e] >> 8], 1);
    __syncthreads();
    for (int i = threadIdx.x; i < NB; i += 256) {
        int c = h[i];
        if (c) atomicAdd(&bktcnt[i], c);
    }
}

// scan bucket counts -> bktoff[NB+1], bktcur copy (1 block, 512 threads)
__global__ void k_scan(const int* __restrict__ bktcnt, int* __restrict__ bktoff,
                       int* __restrict__ bktcur, int NB) {
    __shared__ int s[512];
    int t = threadIdx.x;
    int v = (t < NB) ? bktcnt[t] : 0;
    s[t] = v;
    __syncthreads();
    for (int off = 1; off < 512; off <<= 1) {
        int a = (t >= off) ? s[t - off] : 0;
        __syncthreads();
        s[t] += a;
        __syncthreads();
    }
    if (t <= NB) {
        int e = s[t] - v;
        bktoff[t] = e;
        if (t < NB) bktcur[t] = e;
    }
}

// partition: rank tile in LDS, write bucket-contiguous runs (full lines)
__global__ __launch_bounds__(256) void k_part(const int* __restrict__ src,
                                              const int* __restrict__ dst,
                                              int* __restrict__ bktcur,
                                              unsigned long long* __restrict__ pairs,
                                              int E, int NB) {
    __shared__ int hist[512], sc[512], base[512], gbase[512];
    __shared__ unsigned long long buf[PTILE];
    int t = threadIdx.x;
    int e0 = blockIdx.x * PTILE;
    int n = min(PTILE, E - e0);

    for (int i = t; i < 512; i += 256) hist[i] = 0;
    __syncthreads();

    int mys[16], myd[16], myb[16], myr[16];
#pragma unroll
    for (int k = 0; k < 16; ++k) {
        int i = t + k * 256;
        bool ok = i < n;
        int d = ok ? dst[e0 + i] : 0;
        int s2 = ok ? src[e0 + i] : 0;
        int b = d >> 8;
        mys[k] = s2; myd[k] = d; myb[k] = b;
        myr[k] = ok ? atomicAdd(&hist[b], 1) : 0;
    }
    __syncthreads();
    // inclusive scan of 512 slots with 256 threads
    sc[t] = hist[t];
    sc[t + 256] = hist[t + 256];
    __syncthreads();
    for (int off = 1; off < 512; off <<= 1) {
        int a = (t >= off) ? sc[t - off] : 0;
        int b2 = (t + 256 >= off) ? sc[t + 256 - off] : 0;
        __syncthreads();
        sc[t] += a;
        sc[t + 256] += b2;
        __syncthreads();
    }
    for (int i = t; i < NB; i += 256) {
        int c = hist[i];
        base[i] = sc[i] - c;
        gbase[i] = c ? atomicAdd(&bktcur[i], c) : 0;
    }
    __syncthreads();
#pragma unroll
    for (int k = 0; k < 16; ++k) {
        int i = t + k * 256;
        if (i < n)
            buf[base[myb[k]] + myr[k]] =
                ((unsigned long long)myd[k] << 32) | (unsigned int)mys[k];
    }
    __syncthreads();
    for (int i = t; i < n; i += 256) {
        unsigned long long p = buf[i];
        int b = (int)(p >> 40);
        pairs[gbase[b] + (i - base[b])] = p;
    }
}

// per-bucket: counts/rowstart/dinv + csr slice (coalesced full-line writes)
__global__ __launch_bounds__(256) void k_build(const unsigned long long* __restrict__ pairs,
                                               const int* __restrict__ bktoff,
                                               int* __restrict__ counts,
                                               int* __restrict__ rowstart,
                                               float* __restrict__ dinv,
                                               int* __restrict__ csr, int N) {
    int b = blockIdx.x, t = threadIdx.x;
    int lo = bktoff[b], hi = bktoff[b + 1], m = hi - lo;
    int node0 = b << 8;
    __shared__ int cnt[256], sc2[256], cur[256];
    __shared__ int csrbuf[CSRCAP];
    cnt[t] = 0;
    __syncthreads();
    for (int i = t; i < m; i += 256) atomicAdd(&cnt[(int)(pairs[lo + i] >> 32) - node0], 1);
    __syncthreads();
    sc2[t] = cnt[t];
    __syncthreads();
    for (int off = 1; off < 256; off <<= 1) {
        int a = (t >= off) ? sc2[t - off] : 0;
        __syncthreads();
        sc2[t] += a;
        __syncthreads();
    }
    int excl = sc2[t] - cnt[t];
    int node = node0 + t;
    if (node < N) {
        counts[node] = cnt[t];
        rowstart[node] = lo + excl;
        dinv[node] = rsqrtf((float)cnt[t] + 1.0f);
    }
    cur[t] = excl;
    __syncthreads();
    if (m <= CSRCAP) {
        for (int i = t; i < m; i += 256) {
            unsigned long long p = pairs[lo + i];
            int r = atomicAdd(&cur[(int)(p >> 32) - node0], 1);
            csrbuf[r] = (int)(unsigned int)p;
        }
        __syncthreads();
        for (int i = t; i < m; i += 256) csr[lo + i] = csrbuf[i];
    } else {  // overflow fallback (never expected)
        for (int i = t; i < m; i += 256) {
            unsigned long long p = pairs[lo + i];
            int r = atomicAdd(&cur[(int)(p >> 32) - node0], 1);
            csr[lo + r] = (int)(unsigned int)p;
        }
    }
}

// ---------- GEMM: hs[i,c] = (sum_k a[i,k] * W[c,k]) * dinv[i] ----------
// MODE 0: A = f32 (layer 1, converts on the fly)
// MODE 1: A = bf16 pre-activations; apply per-channel relu(v*bnA[k]+bnB[k]) while loading
__global__ void k_dummy() {}
template <int MODE>
__global__ __launch_bounds__(256) void k_gemm(const void* __restrict__ Ain,
                                              const unsigned short* __restrict__ Wb,
                                              const float* __restrict__ dinv,
                                              const float* __restrict__ bnA,
                                              const float* __restrict__ bnB,
                                              unsigned short* __restrict__ hs, int N) {
    int wv = threadIdx.x >> 6;
    int lane = threadIdx.x & 63;
    int ln = lane & 15, hi = lane >> 4;
    int rowbase = blockIdx.x * 64 + wv * 16;
    int arow = rowbase + ln;
    bool aok = arow < N;

    bf16x8 a[4];
#pragma unroll
    for (int kc = 0; kc < 4; ++kc) {
        int kb = kc * 32 + hi * 8;
        unsigned int w2[4];
        if (MODE == 0) {
            const float4* Ap = (const float4*)((const float*)Ain + (size_t)arow * 128 + kb);
            float4 f0 = aok ? Ap[0] : make_float4(0.f, 0.f, 0.f, 0.f);
            float4 f1 = aok ? Ap[1] : make_float4(0.f, 0.f, 0.f, 0.f);
            w2[0] = pack2(f0.x, f0.y);
            w2[1] = pack2(f0.z, f0.w);
            w2[2] = pack2(f1.x, f1.y);
            w2[3] = pack2(f1.z, f1.w);
        } else {
            const uintx4* Ap =
                (const uintx4*)((const unsigned short*)Ain + (size_t)arow * 128 + kb);
            uintx4 zz = {0u, 0u, 0u, 0u};
            uintx4 u = aok ? Ap[0] : zz;
#pragma unroll
            for (int j = 0; j < 4; ++j) {
                int c = kb + 2 * j;
                float lo = fmaxf(bflo(u[j]) * bnA[c] + bnB[c], 0.f);
                float h2 = fmaxf(bfhi(u[j]) * bnA[c + 1] + bnB[c + 1], 0.f);
                w2[j] = pack2(lo, h2);
            }
        }
        uintx4 uu = {w2[0], w2[1], w2[2], w2[3]};
        a[kc] = __builtin_bit_cast(bf16x8, uu);
    }

    float dv[4];
    int er0 = rowbase + hi * 4;
#pragma unroll
    for (int q = 0; q < 4; ++q) dv[q] = (er0 + q < N) ? dinv[er0 + q] : 0.f;

#pragma unroll
    for (int ct = 0; ct < 8; ++ct) {
        int col = ct * 16 + ln;
        const uintx4* Wp = (const uintx4*)(Wb + col * 128 + hi * 8);
        f32x4 acc = {0.f, 0.f, 0.f, 0.f};
#pragma unroll
        for (int kc = 0; kc < 4; ++kc) {
            bf16x8 bfr = __builtin_bit_cast(bf16x8, Wp[kc * 4]);
            acc = __builtin_amdgcn_mfma_f32_16x16x32_bf16(a[kc], bfr, acc, 0, 0, 0);
        }
#pragma unroll
        for (int q = 0; q < 4; ++q) {
            int r = er0 + q;
            if (r < N) hs[(size_t)r * 128 + col] = (unsigned short)f2bf(acc[q] * dv[q]);
        }
    }
}

// ---------- gather ----------
template <int FINAL>
__global__ __launch_bounds__(256) void k_gather(const unsigned int* __restrict__ hs2,
                                                const int* __restrict__ csr,
                                                const int* __restrict__ rowstart,
                                                const int* __restrict__ counts,
                                                const float* __restrict__ dinv,
                                                unsigned int* __restrict__ pre2,
                                                float* __restrict__ outf,
                                                const float* __restrict__ bias, int N) {
    int lane = threadIdx.x & 63;
    int w = blockIdx.x * (blockDim.x >> 6) + (threadIdx.x >> 6);
    int nw = gridDim.x * (blockDim.x >> 6);
    for (int i = w; i < N; i += nw) {
        int st = rowstart[i], cnt = counts[i];
        unsigned int us = hs2[(size_t)i * 64 + lane];
        float s0 = bflo(us), s1 = bfhi(us);
        int j = 0;
        for (; j + 4 <= cnt; j += 4) {
            int e0 = csr[st + j], e1 = csr[st + j + 1], e2 = csr[st + j + 2],
                e3 = csr[st + j + 3];
            unsigned int u0 = hs2[(size_t)e0 * 64 + lane];
            unsigned int u1 = hs2[(size_t)e1 * 64 + lane];
            unsigned int u2 = hs2[(size_t)e2 * 64 + lane];
            unsigned int u3 = hs2[(size_t)e3 * 64 + lane];
            s0 += bflo(u0) + bflo(u1) + bflo(u2) + bflo(u3);
            s1 += bfhi(u0) + bfhi(u1) + bfhi(u2) + bfhi(u3);
        }
        for (; j < cnt; ++j) {
            unsigned int u = hs2[(size_t)csr[st + j] * 64 + lane];
            s0 += bflo(u);
            s1 += bfhi(u);
        }
        float sc = dinv[i];
        s0 *= sc;
        s1 *= sc;
        if (FINAL) {
            float2 o;
            o.x = s0 + bias[2 * lane];
            o.y = s1 + bias[2 * lane + 1];
            ((float2*)outf)[(size_t)i * 64 + lane] = o;
        } else {
            pre2[(size_t)i * 64 + lane] = pack2(s0, s1);
        }
    }
}

// ---------- BN ----------
__global__ __launch_bounds__(256) void k_stats(const unsigned int* __restrict__ pre2,
                                               float* __restrict__ sums,
                                               float* __restrict__ sumsq, int N) {
    int c2 = threadIdx.x & 63, h = threadIdx.x >> 6;
    int r0 = blockIdx.x * 512;
    int r1 = min(N, r0 + 512);
    float s0 = 0.f, s1 = 0.f, q0 = 0.f, q1 = 0.f;
    for (int r = r0 + h; r < r1; r += 4) {
        unsigned int u = pre2[(size_t)r * 64 + c2];
        float a = bflo(u), b = bfhi(u);
        s0 += a; s1 += b; q0 += a * a; q1 += b * b;
    }
    __shared__ float red[4][64][4];
    red[h][c2][0] = s0; red[h][c2][1] = s1; red[h][c2][2] = q0; red[h][c2][3] = q1;
    __syncthreads();
    if (h == 0) {
        for (int hh = 1; hh < 4; ++hh) {
            s0 += red[hh][c2][0]; s1 += red[hh][c2][1];
            q0 += red[hh][c2][2]; q1 += red[hh][c2][3];
        }
        atomicAdd(&sums[2 * c2], s0);
        atomicAdd(&sums[2 * c2 + 1], s1);
        atomicAdd(&sumsq[2 * c2], q0);
        atomicAdd(&sumsq[2 * c2 + 1], q1);
    }
}

__global__ void k_bnfin(const float* __restrict__ g, const float* __restrict__ beta,
                        float* __restrict__ sums, float* __restrict__ sumsq,
                        float* __restrict__ bnA, float* __restrict__ bnB, float invN) {
    int c = threadIdx.x;
    if (c < 128) {
        float m = sums[c] * invN;
        float var = sumsq[c] * invN - m * m;
        float istd = rsqrtf(var + 1e-5f);
        float A = g[c] * istd;
        bnA[c] = A;
        bnB[c] = beta[c] - m * A;
        sums[c] = 0.f;
        sumsq[c] = 0.f;
    }
}

// ---------- host ----------
extern "C" void kernel_launch(void* const* d_in, const int* in_sizes, int n_in,
                              void* d_out, int out_size, void* d_ws, size_t ws_size,
                              hipStream_t stream) {
    const float* x = (const float*)d_in[0];
    const int* ei = (const int*)d_in[1];
    const float* W1 = (const float*)d_in[2];
    const float* g1 = (const float*)d_in[4];
    const float* be1 = (const float*)d_in[5];
    const float* W2 = (const float*)d_in[6];
    const float* g2 = (const float*)d_in[8];
    const float* be2 = (const float*)d_in[9];
    const float* W3 = (const float*)d_in[10];
    const float* b3 = (const float*)d_in[11];

    int N = in_sizes[0] / 128;
    int E = in_sizes[1] / 2;
    int NB = (N + 255) >> 8;
    const int* srcp = ei;
    const int* dstp = ei + E;

    char* w = (char*)d_ws;
    auto alloc = [&](size_t b) { char* p = w; w += (b + 255) & ~(size_t)255; return p; };
    int* counts = (int*)alloc((size_t)N * 4);
    int* rowstart = (int*)alloc((size_t)N * 4);
    float* dinv = (float*)alloc((size_t)N * 4);
    int* bktcnt = (int*)alloc(2048);
    int* bktoff = (int*)alloc(2048 + 4);
    int* bktcur = (int*)alloc(2048);
    float* sums = (float*)alloc(512);
    float* sumsq = (float*)alloc(512);
    float* bnA = (float*)alloc(512);
    float* bnB = (float*)alloc(512);
    int* csr = (int*)alloc((size_t)E * 4);
    unsigned long long* pairs = (unsigned long long*)alloc((size_t)E * 8);
    unsigned short* wb1 = (unsigned short*)alloc(16384 * 2);
    unsigned short* wb2 = (unsigned short*)alloc(16384 * 2);
    unsigned short* wb3 = (unsigned short*)alloc(16384 * 2);
    unsigned short* hs = (unsigned short*)alloc((size_t)N * 128 * 2);
    unsigned short* pre = (unsigned short*)alloc((size_t)N * 128 * 2);
    (void)ws_size; (void)n_in; (void)out_size;

    int gemm_grid = (N + 63) / 64;
    int npart = (E + PTILE - 1) / PTILE;
    float invN = 1.0f / (float)N;

    // CSR build (bucketed, write-amplification-free)
    k_init<<<1, 512, 0, stream>>>(bktcnt, sums, sumsq, NB);
    k_cvt_w<<<64, 256, 0, stream>>>(W1, W2, W3, wb1, wb2, wb3);
    k_bhist<<<256, 256, 0, stream>>>(dstp, bktcnt, E, NB);
    k_scan<<<1, 512, 0, stream>>>(bktcnt, bktoff, bktcur, NB);
    k_part<<<npart, 256, 0, stream>>>(srcp, dstp, bktcur, pairs, E, NB);
    k_build<<<NB, 256, 0, stream>>>(pairs, bktoff, counts, rowstart, dinv, csr, N);

    // layer 1 (f32 input converted in-GEMM)
    k_gemm<0><<<gemm_grid, 256, 0, stream>>>(x, wb1, dinv, nullptr, nullptr, hs, N);
    k_gather<0><<<2048, 256, 0, stream>>>((const unsigned int*)hs, csr, rowstart, counts, dinv,
                                          (unsigned int*)pre, nullptr, nullptr, N);
    k_stats<<<(N + 511) / 512, 256, 0, stream>>>((const unsigned int*)pre, sums, sumsq, N);
    k_bnfin<<<1, 128, 0, stream>>>(g1, be1, sums, sumsq, bnA, bnB, invN);
    // layer 2 (BN+ReLU fused into GEMM A-load)
    k_gemm<1><<<gemm_grid, 256, 0, stream>>>(pre, wb2, dinv, bnA, bnB, hs, N);
    k_gather<0><<<2048, 256, 0, stream>>>((const unsigned int*)hs, csr, rowstart, counts, dinv,
                                          (unsigned int*)pre, nullptr, nullptr, N);
    k_stats<<<(N + 511) / 512, 256, 0, stream>>>((const unsigned int*)pre, sums, sumsq, N);
    k_bnfin<<<1, 128, 0, stream>>>(g2, be2, sums, sumsq, bnA, bnB, invN);
    // layer 3
    k_gemm<1><<<gemm_grid, 256, 0, stream>>>(pre, wb3, dinv, bnA, bnB, hs, N);
    k_gather<1><<<2048, 256, 0, stream>>>((const unsigned int*)hs, csr, rowstart, counts, dinv,
                                          nullptr, (float*)d_out, b3, N);
}

// Round 3
// 370.344 us; speedup vs baseline: 1.7229x; 1.2483x over previous
//
#include <hip/hip_runtime.h>

typedef __bf16 bf16x8 __attribute__((ext_vector_type(8)));
typedef float f32x4 __attribute__((ext_vector_type(4)));
typedef unsigned int uintx4 __attribute__((ext_vector_type(4)));

#define PTILE 4096
#define CSRCAP 5120

// ---------- bf16 helpers ----------
__device__ __forceinline__ float bflo(unsigned int u) { return __uint_as_float(u << 16); }
__device__ __forceinline__ float bfhi(unsigned int u) { return __uint_as_float(u & 0xffff0000u); }
__device__ __forceinline__ unsigned int f2bf(float f) {
    unsigned int u = __float_as_uint(f);
    return (u + 0x7fffu + ((u >> 16) & 1u)) >> 16;
}
__device__ __forceinline__ unsigned int pack2(float lo, float hi) {
    return (f2bf(hi) << 16) | f2bf(lo);
}

// ---------- setup ----------
__global__ void k_cvt_w(const float* __restrict__ W1, const float* __restrict__ W2,
                        const float* __restrict__ W3, unsigned short* __restrict__ wb1,
                        unsigned short* __restrict__ wb2, unsigned short* __restrict__ wb3) {
    int i = blockIdx.x * blockDim.x + threadIdx.x;
    if (i < 128 * 128) {
        wb1[i] = (unsigned short)f2bf(W1[i]);
        wb2[i] = (unsigned short)f2bf(W2[i]);
        wb3[i] = (unsigned short)f2bf(W3[i]);
    }
}

__global__ void k_init(int* __restrict__ bktcnt, float* __restrict__ pS,
                       float* __restrict__ pQ, int NB) {
    int t = threadIdx.x;
    if (t < NB) bktcnt[t] = 0;
    for (int i = t; i < 4096; i += 512) { pS[i] = 0.f; pQ[i] = 0.f; }
}

__global__ __launch_bounds__(256) void k_bhist(const int* __restrict__ dst,
                                               int* __restrict__ bktcnt, int E, int NB) {
    __shared__ int h[512];
    for (int i = threadIdx.x; i < NB; i += 256) h[i] = 0;
    __syncthreads();
    for (int e = blockIdx.x * blockDim.x + threadIdx.x; e < E; e += gridDim.x * blockDim.x)
        atomicAdd(&h[dst[e] >> 8], 1);
    __syncthreads();
    for (int i = threadIdx.x; i < NB; i += 256) {
        int c = h[i];
        if (c) atomicAdd(&bktcnt[i], c);
    }
}

__global__ void k_scan(const int* __restrict__ bktcnt, int* __restrict__ bktoff,
                       int* __restrict__ bktcur, int NB) {
    __shared__ int s[512];
    int t = threadIdx.x;
    int v = (t < NB) ? bktcnt[t] : 0;
    s[t] = v;
    __syncthreads();
    for (int off = 1; off < 512; off <<= 1) {
        int a = (t >= off) ? s[t - off] : 0;
        __syncthreads();
        s[t] += a;
        __syncthreads();
    }
    if (t <= NB) {
        int e = s[t] - v;
        bktoff[t] = e;
        if (t < NB) bktcur[t] = e;
    }
}

__global__ __launch_bounds__(256) void k_part(const int* __restrict__ src,
                                              const int* __restrict__ dst,
                                              int* __restrict__ bktcur,
                                              unsigned long long* __restrict__ pairs,
                                              int E, int NB) {
    __shared__ int hist[512], sc[512], base[512], gbase[512];
    __shared__ unsigned long long buf[PTILE];
    int t = threadIdx.x;
    int e0 = blockIdx.x * PTILE;
    int n = min(PTILE, E - e0);

    for (int i = t; i < 512; i += 256) hist[i] = 0;
    __syncthreads();

    int mys[16], myd[16], myb[16], myr[16];
#pragma unroll
    for (int k = 0; k < 16; ++k) {
        int i = t + k * 256;
        bool ok = i < n;
        int d = ok ? dst[e0 + i] : 0;
        int s2 = ok ? src[e0 + i] : 0;
        int b = d >> 8;
        mys[k] = s2; myd[k] = d; myb[k] = b;
        myr[k] = ok ? atomicAdd(&hist[b], 1) : 0;
    }
    __syncthreads();
    sc[t] = hist[t];
    sc[t + 256] = hist[t + 256];
    __syncthreads();
    for (int off = 1; off < 512; off <<= 1) {
        int a = (t >= off) ? sc[t - off] : 0;
        int b2 = (t + 256 >= off) ? sc[t + 256 - off] : 0;
        __syncthreads();
        sc[t] += a;
        sc[t + 256] += b2;
        __syncthreads();
    }
    for (int i = t; i < NB; i += 256) {
        int c = hist[i];
        base[i] = sc[i] - c;
        gbase[i] = c ? atomicAdd(&bktcur[i], c) : 0;
    }
    __syncthreads();
#pragma unroll
    for (int k = 0; k < 16; ++k) {
        int i = t + k * 256;
        if (i < n)
            buf[base[myb[k]] + myr[k]] =
                ((unsigned long long)myd[k] << 32) | (unsigned int)mys[k];
    }
    __syncthreads();
    for (int i = t; i < n; i += 256) {
        unsigned long long p = buf[i];
        int b = (int)(p >> 40);
        pairs[gbase[b] + (i - base[b])] = p;
    }
}

__global__ __launch_bounds__(256) void k_build(const unsigned long long* __restrict__ pairs,
                                               const int* __restrict__ bktoff,
                                               int* __restrict__ counts,
                                               int* __restrict__ rowstart,
                                               float* __restrict__ dinv,
                                               int* __restrict__ csr, int N) {
    int b = blockIdx.x, t = threadIdx.x;
    int lo = bktoff[b], hi = bktoff[b + 1], m = hi - lo;
    int node0 = b << 8;
    __shared__ int cnt[256], sc2[256], cur[256];
    __shared__ int csrbuf[CSRCAP];
    cnt[t] = 0;
    __syncthreads();
    for (int i = t; i < m; i += 256) atomicAdd(&cnt[(int)(pairs[lo + i] >> 32) - node0], 1);
    __syncthreads();
    sc2[t] = cnt[t];
    __syncthreads();
    for (int off = 1; off < 256; off <<= 1) {
        int a = (t >= off) ? sc2[t - off] : 0;
        __syncthreads();
        sc2[t] += a;
        __syncthreads();
    }
    int excl = sc2[t] - cnt[t];
    int node = node0 + t;
    if (node < N) {
        counts[node] = cnt[t];
        rowstart[node] = lo + excl;
        dinv[node] = rsqrtf((float)cnt[t] + 1.0f);
    }
    cur[t] = excl;
    __syncthreads();
    if (m <= CSRCAP) {
        for (int i = t; i < m; i += 256) {
            unsigned long long p = pairs[lo + i];
            int r = atomicAdd(&cur[(int)(p >> 32) - node0], 1);
            csrbuf[r] = (int)(unsigned int)p;
        }
        __syncthreads();
        for (int i = t; i < m; i += 256) csr[lo + i] = csrbuf[i];
    } else {
        for (int i = t; i < m; i += 256) {
            unsigned long long p = pairs[lo + i];
            int r = atomicAdd(&cur[(int)(p >> 32) - node0], 1);
            csr[lo + r] = (int)(unsigned int)p;
        }
    }
}

// ---------- GEMM ----------
template <int MODE>
__global__ __launch_bounds__(256) void k_gemm(const void* __restrict__ Ain,
                                              const unsigned short* __restrict__ Wb,
                                              const float* __restrict__ dinv,
                                              const float* __restrict__ bnA,
                                              const float* __restrict__ bnB,
                                              unsigned short* __restrict__ hs, int N) {
    int wv = threadIdx.x >> 6;
    int lane = threadIdx.x & 63;
    int ln = lane & 15, hi = lane >> 4;
    int rowbase = blockIdx.x * 64 + wv * 16;
    int arow = rowbase + ln;
    bool aok = arow < N;

    bf16x8 a[4];
#pragma unroll
    for (int kc = 0; kc < 4; ++kc) {
        int kb = kc * 32 + hi * 8;
        unsigned int w2[4];
        if (MODE == 0) {
            const float4* Ap = (const float4*)((const float*)Ain + (size_t)arow * 128 + kb);
            float4 f0 = aok ? Ap[0] : make_float4(0.f, 0.f, 0.f, 0.f);
            float4 f1 = aok ? Ap[1] : make_float4(0.f, 0.f, 0.f, 0.f);
            w2[0] = pack2(f0.x, f0.y);
            w2[1] = pack2(f0.z, f0.w);
            w2[2] = pack2(f1.x, f1.y);
            w2[3] = pack2(f1.z, f1.w);
        } else {
            const uintx4* Ap =
                (const uintx4*)((const unsigned short*)Ain + (size_t)arow * 128 + kb);
            uintx4 zz = {0u, 0u, 0u, 0u};
            uintx4 u = aok ? Ap[0] : zz;
#pragma unroll
            for (int j = 0; j < 4; ++j) {
                int c = kb + 2 * j;
                float lo = fmaxf(bflo(u[j]) * bnA[c] + bnB[c], 0.f);
                float h2 = fmaxf(bfhi(u[j]) * bnA[c + 1] + bnB[c + 1], 0.f);
                w2[j] = pack2(lo, h2);
            }
        }
        uintx4 uu = {w2[0], w2[1], w2[2], w2[3]};
        a[kc] = __builtin_bit_cast(bf16x8, uu);
    }

    float dv[4];
    int er0 = rowbase + hi * 4;
#pragma unroll
    for (int q = 0; q < 4; ++q) dv[q] = (er0 + q < N) ? dinv[er0 + q] : 0.f;

#pragma unroll
    for (int ct = 0; ct < 8; ++ct) {
        int col = ct * 16 + ln;
        const uintx4* Wp = (const uintx4*)(Wb + col * 128 + hi * 8);
        f32x4 acc = {0.f, 0.f, 0.f, 0.f};
#pragma unroll
        for (int kc = 0; kc < 4; ++kc) {
            bf16x8 bfr = __builtin_bit_cast(bf16x8, Wp[kc * 4]);
            acc = __builtin_amdgcn_mfma_f32_16x16x32_bf16(a[kc], bfr, acc, 0, 0, 0);
        }
#pragma unroll
        for (int q = 0; q < 4; ++q) {
            int r = er0 + q;
            if (r < N) hs[(size_t)r * 128 + col] = (unsigned short)f2bf(acc[q] * dv[q]);
        }
    }
}

// ---------- gather (v2: index preload + 8-wide rotated pipeline + fused BN stats) ----------
template <int FINAL>
__global__ __launch_bounds__(256) void k_gather(const unsigned int* __restrict__ hs2,
                                                const int* __restrict__ csr,
                                                const int* __restrict__ rowstart,
                                                const int* __restrict__ counts,
                                                const float* __restrict__ dinv,
                                                unsigned int* __restrict__ pre2,
                                                float* __restrict__ outf,
                                                const float* __restrict__ bias,
                                                float* __restrict__ pS,
                                                float* __restrict__ pQ, int N) {
    int lane = threadIdx.x & 63;
    int w = blockIdx.x * 4 + (threadIdx.x >> 6);
    int nw = gridDim.x * 4;
    float ws0 = 0.f, ws1 = 0.f, wq0 = 0.f, wq1 = 0.f;

    for (int i = w; i < N; i += nw) {
        int st = rowstart[i], cnt = counts[i];
        unsigned int us = hs2[(size_t)i * 64 + lane];
        float s0 = bflo(us), s1 = bfhi(us);

        if (cnt <= 64) {
            int idx = (lane < cnt) ? csr[st + lane] : 0;
            int nfull = cnt & ~7;
            if (nfull) {
                int e[8];
                unsigned int u[8];
#pragma unroll
                for (int k = 0; k < 8; ++k) e[k] = __shfl(idx, k, 64);
#pragma unroll
                for (int k = 0; k < 8; ++k) u[k] = hs2[(size_t)e[k] * 64 + lane];
                for (int j = 8; j < nfull; j += 8) {
                    int en[8];
                    unsigned int un[8];
#pragma unroll
                    for (int k = 0; k < 8; ++k) en[k] = __shfl(idx, j + k, 64);
#pragma unroll
                    for (int k = 0; k < 8; ++k) un[k] = hs2[(size_t)en[k] * 64 + lane];
#pragma unroll
                    for (int k = 0; k < 8; ++k) { s0 += bflo(u[k]); s1 += bfhi(u[k]); }
#pragma unroll
                    for (int k = 0; k < 8; ++k) u[k] = un[k];
                }
#pragma unroll
                for (int k = 0; k < 8; ++k) { s0 += bflo(u[k]); s1 += bfhi(u[k]); }
            }
            for (int j = nfull; j < cnt; ++j) {
                int e0 = __shfl(idx, j, 64);
                unsigned int u = hs2[(size_t)e0 * 64 + lane];
                s0 += bflo(u);
                s1 += bfhi(u);
            }
        } else {  // generic fallback (cnt > 64: effectively never for this graph)
            for (int j = 0; j < cnt; ++j) {
                unsigned int u = hs2[(size_t)csr[st + j] * 64 + lane];
                s0 += bflo(u);
                s1 += bfhi(u);
            }
        }

        float sc = dinv[i];
        s0 *= sc;
        s1 *= sc;
        if (FINAL) {
            float2 o;
            o.x = s0 + bias[2 * lane];
            o.y = s1 + bias[2 * lane + 1];
            ((float2*)outf)[(size_t)i * 64 + lane] = o;
        } else {
            pre2[(size_t)i * 64 + lane] = pack2(s0, s1);
            ws0 += s0; ws1 += s1;
            wq0 += s0 * s0; wq1 += s1 * s1;
        }
    }

    if (!FINAL) {
        __shared__ float red[4][64][4];
        int h = threadIdx.x >> 6;
        red[h][lane][0] = ws0; red[h][lane][1] = ws1;
        red[h][lane][2] = wq0; red[h][lane][3] = wq1;
        __syncthreads();
        if (h == 0) {
#pragma unroll
            for (int hh = 1; hh < 4; ++hh) {
                ws0 += red[hh][lane][0]; ws1 += red[hh][lane][1];
                wq0 += red[hh][lane][2]; wq1 += red[hh][lane][3];
            }
            int slot = (blockIdx.x & 31) * 128;
            atomicAdd(&pS[slot + 2 * lane], ws0);
            atomicAdd(&pS[slot + 2 * lane + 1], ws1);
            atomicAdd(&pQ[slot + 2 * lane], wq0);
            atomicAdd(&pQ[slot + 2 * lane + 1], wq1);
        }
    }
}

// reduce 32 slices -> bnA/bnB; re-zero partials for next layer
__global__ void k_bnfin(const float* __restrict__ g, const float* __restrict__ beta,
                        float* __restrict__ pS, float* __restrict__ pQ,
                        float* __restrict__ bnA, float* __restrict__ bnB, float invN) {
    int c = threadIdx.x;
    if (c < 128) {
        float s = 0.f, q = 0.f;
        for (int k = 0; k < 32; ++k) {
            s += pS[k * 128 + c]; q += pQ[k * 128 + c];
            pS[k * 128 + c] = 0.f; pQ[k * 128 + c] = 0.f;
        }
        float m = s * invN;
        float var = q * invN - m * m;
        float istd = rsqrtf(var + 1e-5f);
        float A = g[c] * istd;
        bnA[c] = A;
        bnB[c] = beta[c] - m * A;
    }
}

// ---------- host ----------
extern "C" void kernel_launch(void* const* d_in, const int* in_sizes, int n_in,
                              void* d_out, int out_size, void* d_ws, size_t ws_size,
                              hipStream_t stream) {
    const float* x = (const float*)d_in[0];
    const int* ei = (const int*)d_in[1];
    const float* W1 = (const float*)d_in[2];
    const float* g1 = (const float*)d_in[4];
    const float* be1 = (const float*)d_in[5];
    const float* W2 = (const float*)d_in[6];
    const float* g2 = (const float*)d_in[8];
    const float* be2 = (const float*)d_in[9];
    const float* W3 = (const float*)d_in[10];
    const float* b3 = (const float*)d_in[11];

    int N = in_sizes[0] / 128;
    int E = in_sizes[1] / 2;
    int NB = (N + 255) >> 8;
    const int* srcp = ei;
    const int* dstp = ei + E;

    char* w = (char*)d_ws;
    auto alloc = [&](size_t b) { char* p = w; w += (b + 255) & ~(size_t)255; return p; };
    int* counts = (int*)alloc((size_t)N * 4);
    int* rowstart = (int*)alloc((size_t)N * 4);
    float* dinv = (float*)alloc((size_t)N * 4);
    int* bktcnt = (int*)alloc(2048);
    int* bktoff = (int*)alloc(2048 + 4);
    int* bktcur = (int*)alloc(2048);
    float* pS = (float*)alloc(4096 * 4);
    float* pQ = (float*)alloc(4096 * 4);
    float* bnA = (float*)alloc(512);
    float* bnB = (float*)alloc(512);
    int* csr = (int*)alloc((size_t)E * 4);
    unsigned long long* pairs = (unsigned long long*)alloc((size_t)E * 8);
    unsigned short* wb1 = (unsigned short*)alloc(16384 * 2);
    unsigned short* wb2 = (unsigned short*)alloc(16384 * 2);
    unsigned short* wb3 = (unsigned short*)alloc(16384 * 2);
    unsigned short* hs = (unsigned short*)alloc((size_t)N * 128 * 2);
    unsigned short* pre = (unsigned short*)alloc((size_t)N * 128 * 2);
    (void)ws_size; (void)n_in; (void)out_size;

    int gemm_grid = (N + 63) / 64;
    int npart = (E + PTILE - 1) / PTILE;
    float invN = 1.0f / (float)N;

    // CSR build
    k_init<<<1, 512, 0, stream>>>(bktcnt, pS, pQ, NB);
    k_cvt_w<<<64, 256, 0, stream>>>(W1, W2, W3, wb1, wb2, wb3);
    k_bhist<<<256, 256, 0, stream>>>(dstp, bktcnt, E, NB);
    k_scan<<<1, 512, 0, stream>>>(bktcnt, bktoff, bktcur, NB);
    k_part<<<npart, 256, 0, stream>>>(srcp, dstp, bktcur, pairs, E, NB);
    k_build<<<NB, 256, 0, stream>>>(pairs, bktoff, counts, rowstart, dinv, csr, N);

    // layer 1
    k_gemm<0><<<gemm_grid, 256, 0, stream>>>(x, wb1, dinv, nullptr, nullptr, hs, N);
    k_gather<0><<<2048, 256, 0, stream>>>((const unsigned int*)hs, csr, rowstart, counts, dinv,
                                          (unsigned int*)pre, nullptr, nullptr, pS, pQ, N);
    k_bnfin<<<1, 128, 0, stream>>>(g1, be1, pS, pQ, bnA, bnB, invN);
    // layer 2
    k_gemm<1><<<gemm_grid, 256, 0, stream>>>(pre, wb2, dinv, bnA, bnB, hs, N);
    k_gather<0><<<2048, 256, 0, stream>>>((const unsigned int*)hs, csr, rowstart, counts, dinv,
                                          (unsigned int*)pre, nullptr, nullptr, pS, pQ, N);
    k_bnfin<<<1, 128, 0, stream>>>(g2, be2, pS, pQ, bnA, bnB, invN);
    // layer 3
    k_gemm<1><<<gemm_grid, 256, 0, stream>>>(pre, wb3, dinv, bnA, bnB, hs, N);
    k_gather<1><<<2048, 256, 0, stream>>>((const unsigned int*)hs, csr, rowstart, counts, dinv,
                                          nullptr, (float*)d_out, b3, nullptr, nullptr, N);
}